// Round 1
// baseline (645.183 us; speedup 1.0000x reference)
//
#include <hip/hip_runtime.h>
#include <math.h>

#define DIM   1024
#define HALF  512
#define NROWS 65536

// ---- workspace layout (float offsets) ----
#define OFF_SCAL   0                      // [8] scalars; scal[3] = 1/sum(exp)
#define OFF_QN     8                      // [1024] l2norm(q_init)
#define OFF_PVEC   1032                   // [1024] Wk @ q
#define OFF_S      2056                   // [65536] raw scores
#define OFF_INVN   (OFF_S + NROWS)        // [65536] 1/||k_init_i||
#define OFF_COEFF  (OFF_INVN + NROWS)     // [65536] exp(z_i) * invn_i
#define OFF_QACC   (OFF_COEFF + NROWS)    // [512]  q = qn @ Wq (atomic acc)
#define OFF_WACC   (OFF_QACC + HALF)      // [1024] w = attn @ kn (atomic acc)
#define OFF_OVACC  (OFF_WACC + DIM)       // [1024] w @ Wv (atomic acc)
#define OFF_OUTACC (OFF_OVACC + DIM)      // [1024] (ov+bv) @ Wm (atomic acc)
#define OFF_END    (OFF_OUTACC + DIM)

// K1a: qn = q_init / max(||q_init||, 1e-12)
__global__ void k_qnorm(const float* __restrict__ q_init, float* __restrict__ qn) {
    __shared__ float red[1024];
    int t = threadIdx.x;
    float v = q_init[t];
    red[t] = v * v;
    __syncthreads();
    for (int s = 512; s > 0; s >>= 1) {
        if (t < s) red[t] += red[t + s];
        __syncthreads();
    }
    float inv = 1.0f / fmaxf(sqrtf(red[0]), 1e-12f);
    qn[t] = v * inv;
}

// Generic weighted column-sum: out[c] += sum_r (coeff[r] (+cbias[r])) * (*cscale) * M[r][c]
// ncols4 <= 256 (one float4 per thread). Atomic accumulation across blocks.
__global__ void k_colsum(const float* __restrict__ M,
                         const float* __restrict__ coeff,
                         const float* __restrict__ cbias,
                         const float* __restrict__ cscale,
                         float* __restrict__ out,
                         int nrows, int ncols4, int rowsPerBlock) {
    int t = threadIdx.x;
    if (t >= ncols4) return;
    int r0 = blockIdx.x * rowsPerBlock;
    int r1 = min(r0 + rowsPerBlock, nrows);
    float sc = cscale ? cscale[0] : 1.0f;
    const float4* M4 = (const float4*)M;
    float4 acc = make_float4(0.f, 0.f, 0.f, 0.f);
    for (int r = r0; r < r1; ++r) {
        float c = coeff[r];
        if (cbias) c += cbias[r];
        c *= sc;
        float4 m = M4[(size_t)r * ncols4 + t];
        acc.x += c * m.x; acc.y += c * m.y; acc.z += c * m.z; acc.w += c * m.w;
    }
    atomicAdd(&out[t * 4 + 0], acc.x);
    atomicAdd(&out[t * 4 + 1], acc.y);
    atomicAdd(&out[t * 4 + 2], acc.z);
    atomicAdd(&out[t * 4 + 3], acc.w);
}

// K1c: pvec[d] = sum_j Wk[d][j] * (qacc[j] + bq[j]); one wave per row d.
__global__ void k_pvec(const float* __restrict__ Wk,
                       const float* __restrict__ qacc,
                       const float* __restrict__ bq,
                       float* __restrict__ pvec) {
    __shared__ float q[HALF];
    int t = threadIdx.x; // 256
    for (int j = t; j < HALF; j += 256) q[j] = qacc[j] + bq[j];
    __syncthreads();
    int wave = t >> 6, lane = t & 63;
    int d = blockIdx.x * 4 + wave;
    const float* row = Wk + (size_t)d * HALF;
    float acc = 0.f;
    #pragma unroll
    for (int j0 = 0; j0 < HALF; j0 += 64) acc += row[j0 + lane] * q[j0 + lane];
    #pragma unroll
    for (int o = 32; o > 0; o >>= 1) acc += __shfl_down(acc, o);
    if (lane == 0) pvec[d] = acc;
}

// K2: per row i: s_i = dot(k_init[i], pvec)/max(||k_init[i]||,eps); also 1/||.||
// One wave per row, float4 loads. Grid = NROWS/4 blocks x 256 threads.
__global__ void k_scores(const float* __restrict__ K,
                         const float* __restrict__ pvec,
                         float* __restrict__ svals,
                         float* __restrict__ invn) {
    __shared__ float4 p4[256];
    int t = threadIdx.x;
    p4[t] = ((const float4*)pvec)[t];
    __syncthreads();
    int wave = t >> 6, lane = t & 63;
    int row = blockIdx.x * 4 + wave;
    const float4* k4 = (const float4*)K + (size_t)row * 256;
    float dot = 0.f, sq = 0.f;
    #pragma unroll
    for (int i = 0; i < 4; ++i) {
        int idx = lane + i * 64;
        float4 v = k4[idx];
        float4 p = p4[idx];
        dot += v.x * p.x + v.y * p.y + v.z * p.z + v.w * p.w;
        sq  += v.x * v.x + v.y * v.y + v.z * v.z + v.w * v.w;
    }
    #pragma unroll
    for (int o = 32; o > 0; o >>= 1) {
        dot += __shfl_down(dot, o);
        sq  += __shfl_down(sq, o);
    }
    if (lane == 0) {
        float inv = 1.0f / fmaxf(sqrtf(sq), 1e-12f);
        svals[row] = dot * inv;
        invn[row]  = inv;
    }
}

// K3: mean/unbiased-std -> z=clip((s-mean)/(std+1e-8)) -> coeff=exp(z)*invn,
// scal[3] = 1/sum(exp(z)). Single block, 1024 threads.
__global__ void k_softmax(const float* __restrict__ svals,
                          const float* __restrict__ invn,
                          float* __restrict__ coeff,
                          float* __restrict__ scal) {
    __shared__ float rs[1024], rq[1024];
    int t = threadIdx.x;
    float sum = 0.f, ssq = 0.f;
    for (int i = t; i < NROWS; i += 1024) {
        float s = svals[i];
        sum += s; ssq += s * s;
    }
    rs[t] = sum; rq[t] = ssq;
    __syncthreads();
    for (int s = 512; s > 0; s >>= 1) {
        if (t < s) { rs[t] += rs[t + s]; rq[t] += rq[t + s]; }
        __syncthreads();
    }
    float mean = rs[0] / (float)NROWS;
    float var  = (rq[0] - (float)NROWS * mean * mean) / (float)(NROWS - 1);
    float rstd = 1.0f / (sqrtf(fmaxf(var, 0.0f)) + 1e-8f);
    __syncthreads(); // before reusing rs
    float esum = 0.f;
    for (int i = t; i < NROWS; i += 1024) {
        float z = (svals[i] - mean) * rstd;
        z = fminf(fmaxf(z, -10.0f), 10.0f);
        float e = expf(z);   // z in [-10,10]: no overflow, no max-shift needed
        esum += e;
        coeff[i] = e * invn[i];
    }
    rs[t] = esum;
    __syncthreads();
    for (int s = 512; s > 0; s >>= 1) {
        if (t < s) rs[t] += rs[t + s];
        __syncthreads();
    }
    if (t == 0) scal[3] = 1.0f / rs[0];
}

// K6: out = g*q_init + (1-g)*(outacc + bm), g = sigmoid(gamma)
__global__ void k_final(const float* __restrict__ q_init,
                        const float* __restrict__ outacc,
                        const float* __restrict__ bm,
                        const float* __restrict__ gamma,
                        float* __restrict__ out) {
    int t = threadIdx.x;
    float g = 1.0f / (1.0f + expf(-gamma[0]));
    out[t] = g * q_init[t] + (1.0f - g) * (outacc[t] + bm[t]);
}

extern "C" void kernel_launch(void* const* d_in, const int* in_sizes, int n_in,
                              void* d_out, int out_size, void* d_ws, size_t ws_size,
                              hipStream_t stream) {
    const float* q_init = (const float*)d_in[0];
    const float* k_init = (const float*)d_in[1];
    const float* Wq     = (const float*)d_in[2];
    const float* bq     = (const float*)d_in[3];
    const float* Wk     = (const float*)d_in[4];
    // d_in[5] = bk: constant shift of all scores -> cancels in standardization
    const float* Wv     = (const float*)d_in[6];
    const float* bv     = (const float*)d_in[7];
    const float* Wm     = (const float*)d_in[8];
    const float* bm     = (const float*)d_in[9];
    const float* gamma  = (const float*)d_in[10];
    float* out = (float*)d_out;
    float* ws  = (float*)d_ws;

    float* scal   = ws + OFF_SCAL;
    float* qn     = ws + OFF_QN;
    float* pvec   = ws + OFF_PVEC;
    float* svals  = ws + OFF_S;
    float* invn   = ws + OFF_INVN;
    float* coeff  = ws + OFF_COEFF;
    float* qacc   = ws + OFF_QACC;
    float* wacc   = ws + OFF_WACC;
    float* ovacc  = ws + OFF_OVACC;
    float* outacc = ws + OFF_OUTACC;

    // zero the atomic accumulators (ws is poisoned 0xAA before every call)
    hipMemsetAsync(qacc, 0, (size_t)(OFF_END - OFF_QACC) * sizeof(float), stream);

    k_qnorm<<<1, 1024, 0, stream>>>(q_init, qn);
    // q = qn @ Wq  (bq folded in at consumption)
    k_colsum<<<32, 256, 0, stream>>>(Wq, qn, nullptr, nullptr, qacc,
                                     DIM, HALF / 4, DIM / 32);
    // pvec = Wk @ (q + bq)
    k_pvec<<<DIM / 4, 256, 0, stream>>>(Wk, qacc, bq, pvec);
    // pass 1 over k_init: raw scores + inverse norms
    k_scores<<<NROWS / 4, 256, 0, stream>>>(k_init, pvec, svals, invn);
    // softmax stats + per-row coefficients
    k_softmax<<<1, 1024, 0, stream>>>(svals, invn, coeff, scal);
    // pass 2 over k_init: w = sum_i (e_i/sumexp) * invn_i * k_init[i,:]
    k_colsum<<<1024, 256, 0, stream>>>(k_init, coeff, nullptr, scal + 3, wacc,
                                       NROWS, DIM / 4, NROWS / 1024);
    // ov = w @ Wv   (bv folded into next stage's coeff)
    k_colsum<<<64, 256, 0, stream>>>(Wv, wacc, nullptr, nullptr, ovacc,
                                     DIM, DIM / 4, DIM / 64);
    // outacc = (ov + bv) @ Wm
    k_colsum<<<64, 256, 0, stream>>>(Wm, ovacc, bv, nullptr, outacc,
                                     DIM, DIM / 4, DIM / 64);
    // out = g*q_init + (1-g)*(outacc + bm)
    k_final<<<1, 1024, 0, stream>>>(q_init, outacc, bm, gamma, out);
}